// Round 2
// baseline (117.245 us; speedup 1.0000x reference)
//
#include <hip/hip_runtime.h>
#include <math.h>

// Retention via chunked linear attention.
//   Q' = (xq@W) * gamma^{-n}/sqrt(D);  K'' = (xk@W) * gamma^{m}/sqrt(rowsum[m])
//   s[b,n]   = Q'_n . prefix(K'')_n            (exact row-sum of pre-norm scores)
//   V'_m     = (xv@W)_m / max(|s[b,m]|,1)      (column normalization folded into V)
//   out_n    = Q'_n @ SE_c + tril(Q'K''^T) @ V'   (SE_c = exclusive chunk prefix of K''V'^T)

constexpr int B = 8, S = 2048, D = 128;
constexpr int C = 64, NC = S / C;   // chunk size / count
constexpr int BS = B * S;
#define GAMMA_F 0.9865f

// ---------------- K0: per-position decay scalars (f64 closed form) ----------------
__global__ void k_scales(float* __restrict__ qs, float* __restrict__ ks) {
  int n = blockIdx.x * 256 + threadIdx.x;
  if (n >= S) return;
  double g = (double)GAMMA_F;          // match jnp.float32(gamma)
  double lg = log(g);
  double gmn = exp(-lg * (double)n);   // gamma^{-n}
  double gn  = exp(lg * (double)n);    // gamma^{n}
  double ginv = 1.0 / g;
  // rowsum[n] = sum_{j=0}^{n} gamma^{-j} = (ginv^{n+1}-1)/(ginv-1)
  double rs = (exp(log(ginv) * (double)(n + 1)) - 1.0) / (ginv - 1.0);
  qs[n] = (float)(gmn / sqrt(128.0));
  ks[n] = (float)(gn / sqrt(rs));
}

// ---------------- K1: projections Q',K'',V = (x@W)*scale ----------------
// grid (BS/64, 3), block 256. Tile: 64 rows x 128 cols, K=128.
__global__ __launch_bounds__(256) void k_proj(
    const float* __restrict__ xq, const float* __restrict__ xk,
    const float* __restrict__ xv, const float* __restrict__ W,
    const float* __restrict__ qs, const float* __restrict__ ks,
    float* __restrict__ qp, float* __restrict__ kp, float* __restrict__ vp) {
  __shared__ float xs[64][129];   // pad -> 2-way max bank alias (free)
  int mat = blockIdx.y;
  const float* X = (mat == 0) ? xq : ((mat == 1) ? xk : xv);
  float* O = (mat == 0) ? qp : ((mat == 1) ? kp : vp);
  int row0 = blockIdx.x * 64;
  int tid = threadIdx.x;
  for (int i = tid; i < 64 * 128; i += 256)
    xs[i >> 7][i & 127] = X[(size_t)row0 * 128 + i];
  __syncthreads();

  int tcol = tid & 31, trow = tid >> 5;   // 32 col-lanes x 8 row-groups
  float acc[8][4];
#pragma unroll
  for (int i = 0; i < 8; i++)
#pragma unroll
    for (int j = 0; j < 4; j++) acc[i][j] = 0.f;

  for (int k = 0; k < 128; k++) {
    float wv[4];
#pragma unroll
    for (int j = 0; j < 4; j++) wv[j] = W[k * 128 + tcol + 32 * j];
#pragma unroll
    for (int i = 0; i < 8; i++) {
      float xvl = xs[trow * 8 + i][k];
#pragma unroll
      for (int j = 0; j < 4; j++) acc[i][j] = fmaf(xvl, wv[j], acc[i][j]);
    }
  }
#pragma unroll
  for (int i = 0; i < 8; i++) {
    int r = row0 + trow * 8 + i;
    int n = r & (S - 1);
    float sc = (mat == 0) ? qs[n] : ((mat == 1) ? ks[n] : 1.0f);
#pragma unroll
    for (int j = 0; j < 4; j++)
      O[(size_t)r * 128 + tcol + 32 * j] = acc[i][j] * sc;
  }
}

// ---------------- K2: per-chunk column sums of K'' ----------------
__global__ __launch_bounds__(128) void k_chunksum(const float* __restrict__ kp,
                                                  float* __restrict__ cs) {
  int bc = blockIdx.x;      // b*NC + c
  int d = threadIdx.x;
  const float* p = kp + (size_t)bc * C * D + d;
  float a = 0.f;
  for (int j = 0; j < C; j++) a += p[j * D];
  cs[bc * D + d] = a;
}

// ---------------- K3: in-place exclusive prefix over chunks ----------------
__global__ __launch_bounds__(128) void k_csprefix(float* __restrict__ cs) {
  int b = blockIdx.x, d = threadIdx.x;
  float run = 0.f;
  for (int c = 0; c < NC; c++) {
    int idx = (b * NC + c) * D + d;
    float t = cs[idx];
    cs[idx] = run;
    run += t;
  }
}

// ---------------- K4: s[b,n] = Q'_n . P_n ; V' = V / max(|s|,1) (in place) ----------------
__global__ __launch_bounds__(128) void k_svs(
    const float* __restrict__ qp, const float* __restrict__ kp,
    const float* __restrict__ cs, float* __restrict__ vp) {
  __shared__ float ps[C][D + 1];
  __shared__ float sl[C];
  int bc = blockIdx.x;
  int d = threadIdx.x;
  size_t base = (size_t)bc * C * D;
  float run = cs[bc * D + d];               // exclusive prefix over prior chunks
  for (int j = 0; j < C; j++) {
    run += kp[base + (size_t)j * D + d];
    ps[j][d] = run;                          // inclusive full prefix P_n[d]
  }
  __syncthreads();
  int j = d >> 1, h = d & 1;                 // 2 lanes per row
  const float* q = qp + base + (size_t)j * D + h * 64;
  float part = 0.f;
#pragma unroll 8
  for (int i = 0; i < 64; i++) part = fmaf(q[i], ps[j][h * 64 + i], part);
  part += __shfl_xor(part, 1);
  if (h == 0) sl[j] = part;
  __syncthreads();
  for (int idx = d; idx < C * D; idx += 128) {
    int jj = idx >> 7;
    float cdiv = fmaxf(fabsf(sl[jj]), 1.0f);
    vp[base + idx] = vp[base + idx] / cdiv;
  }
}

// ---------------- K5: per-chunk state G_c = K''^T @ V'  (D x D) ----------------
__global__ __launch_bounds__(256) void k_gmat(
    const float* __restrict__ kp, const float* __restrict__ vp,
    float* __restrict__ G) {
  __shared__ float kc[C][D + 1];
  __shared__ float vc[C][D + 1];
  int bc = blockIdx.x;
  int tid = threadIdx.x;
  size_t base = (size_t)bc * C * D;
  for (int i = tid; i < C * D; i += 256) {
    kc[i >> 7][i & 127] = kp[base + i];
    vc[i >> 7][i & 127] = vp[base + i];
  }
  __syncthreads();
  int t2 = tid & 15, t1 = tid >> 4;          // 16x16 thread grid, 8x8 outputs each
  float acc[8][8];
#pragma unroll
  for (int i = 0; i < 8; i++)
#pragma unroll
    for (int j = 0; j < 8; j++) acc[i][j] = 0.f;
  for (int m = 0; m < C; m++) {
    float a[8], bv[8];
#pragma unroll
    for (int i = 0; i < 8; i++) a[i] = kc[m][t1 + 16 * i];
#pragma unroll
    for (int j = 0; j < 8; j++) bv[j] = vc[m][t2 + 16 * j];
#pragma unroll
    for (int i = 0; i < 8; i++)
#pragma unroll
      for (int j = 0; j < 8; j++) acc[i][j] = fmaf(a[i], bv[j], acc[i][j]);
  }
  float* g = G + (size_t)bc * D * D;
#pragma unroll
  for (int i = 0; i < 8; i++)
#pragma unroll
    for (int j = 0; j < 8; j++)
      g[(size_t)(t1 + 16 * i) * D + t2 + 16 * j] = acc[i][j];
}

// ---------------- K6: in-place exclusive scan of G over chunks ----------------
__global__ __launch_bounds__(128) void k_gscan(float* __restrict__ G) {
  int b = blockIdx.x, d1 = blockIdx.y, d2 = threadIdx.x;
  float run = 0.f;
  for (int c = 0; c < NC; c++) {
    size_t idx = (((size_t)(b * NC + c) * D) + d1) * D + d2;
    float t = G[idx];
    G[idx] = run;
    run += t;
  }
}

// ---------------- K7: out = Q' @ SE_c + tril(Q'K''^T) @ V' ----------------
__global__ __launch_bounds__(256) void k_out(
    const float* __restrict__ qp, const float* __restrict__ kp,
    const float* __restrict__ vp, const float* __restrict__ G,
    float* __restrict__ out) {
  __shared__ float qc[C][D + 1];
  __shared__ float kc[C][D + 1];
  __shared__ float vc[C][D + 1];
  __shared__ float al[C][C + 1];
  int bc = blockIdx.x;
  int tid = threadIdx.x;
  size_t base = (size_t)bc * C * D;
  for (int i = tid; i < C * D; i += 256) {
    qc[i >> 7][i & 127] = qp[base + i];
    kc[i >> 7][i & 127] = kp[base + i];
    vc[i >> 7][i & 127] = vp[base + i];
  }
  __syncthreads();
  // phase 1: A = tril(Q'c @ K''c^T)  (64x64)
  {
    int tm = tid & 15, tj = tid >> 4;        // 16x16 threads, 4x4 outputs each
    float a1[4][4];
#pragma unroll
    for (int i = 0; i < 4; i++)
#pragma unroll
      for (int j = 0; j < 4; j++) a1[i][j] = 0.f;
    for (int dd = 0; dd < D; dd++) {
      float qv[4], kv[4];
#pragma unroll
      for (int i = 0; i < 4; i++) qv[i] = qc[tj + 16 * i][dd];
#pragma unroll
      for (int j = 0; j < 4; j++) kv[j] = kc[tm + 16 * j][dd];
#pragma unroll
      for (int i = 0; i < 4; i++)
#pragma unroll
        for (int j = 0; j < 4; j++) a1[i][j] = fmaf(qv[i], kv[j], a1[i][j]);
    }
#pragma unroll
    for (int i = 0; i < 4; i++)
#pragma unroll
      for (int j = 0; j < 4; j++) {
        int jr = tj + 16 * i, mr = tm + 16 * j;
        al[jr][mr] = (jr >= mr) ? a1[i][j] : 0.f;
      }
  }
  __syncthreads();
  // phase 2: inter-chunk (Q' @ SE) + intra-chunk (A @ V')
  int tcol = tid & 31, trow = tid >> 5;
  float acc[8][4];
#pragma unroll
  for (int i = 0; i < 8; i++)
#pragma unroll
    for (int j = 0; j < 4; j++) acc[i][j] = 0.f;
  const float* SE = G + (size_t)bc * D * D;
  for (int d1 = 0; d1 < D; d1++) {
    float sev[4];
#pragma unroll
    for (int j = 0; j < 4; j++) sev[j] = SE[(size_t)d1 * D + tcol + 32 * j];
#pragma unroll
    for (int i = 0; i < 8; i++) {
      float qv = qc[trow * 8 + i][d1];
#pragma unroll
      for (int j = 0; j < 4; j++) acc[i][j] = fmaf(qv, sev[j], acc[i][j]);
    }
  }
  for (int m = 0; m < C; m++) {
    float vv[4];
#pragma unroll
    for (int j = 0; j < 4; j++) vv[j] = vc[m][tcol + 32 * j];
#pragma unroll
    for (int i = 0; i < 8; i++) {
      float av = al[trow * 8 + i][m];
#pragma unroll
      for (int j = 0; j < 4; j++) acc[i][j] = fmaf(av, vv[j], acc[i][j]);
    }
  }
#pragma unroll
  for (int i = 0; i < 8; i++)
#pragma unroll
    for (int j = 0; j < 4; j++)
      out[base + (size_t)(trow * 8 + i) * D + tcol + 32 * j] = acc[i][j];
}

extern "C" void kernel_launch(void* const* d_in, const int* in_sizes, int n_in,
                              void* d_out, int out_size, void* d_ws, size_t ws_size,
                              hipStream_t stream) {
  const float* xq = (const float*)d_in[0];
  const float* xk = (const float*)d_in[1];
  const float* xv = (const float*)d_in[2];
  const float* W  = (const float*)d_in[3];
  float* out = (float*)d_out;

  // ws layout (floats): qp, kp, vp [BS*D each]; G [B*NC*D*D]; cs [B*NC*D]; qs,ks [S each]
  float* ws = (float*)d_ws;
  float* qp = ws;
  float* kp = qp + (size_t)BS * D;
  float* vp = kp + (size_t)BS * D;
  float* G  = vp + (size_t)BS * D;
  float* cs = G + (size_t)B * NC * D * D;
  float* qs = cs + (size_t)B * NC * D;
  float* ks = qs + S;

  hipLaunchKernelGGL(k_scales, dim3(S / 256), dim3(256), 0, stream, qs, ks);
  hipLaunchKernelGGL(k_proj, dim3(BS / 64, 3), dim3(256), 0, stream,
                     xq, xk, xv, W, qs, ks, qp, kp, vp);
  hipLaunchKernelGGL(k_chunksum, dim3(B * NC), dim3(128), 0, stream, kp, cs);
  hipLaunchKernelGGL(k_csprefix, dim3(B), dim3(128), 0, stream, cs);
  hipLaunchKernelGGL(k_svs, dim3(B * NC), dim3(128), 0, stream, qp, kp, cs, vp);
  hipLaunchKernelGGL(k_gmat, dim3(B * NC), dim3(256), 0, stream, kp, vp, G);
  hipLaunchKernelGGL(k_gscan, dim3(B, D), dim3(128), 0, stream, G);
  hipLaunchKernelGGL(k_out, dim3(B * NC), dim3(256), 0, stream, qp, kp, vp, G, out);
}

// Round 3
// 76.058 us; speedup vs baseline: 1.5415x; 1.5415x over previous
//
#include <hip/hip_runtime.h>
#include <math.h>

// Retention via chunked linear attention, bf16-MFMA edition.
//   Q' = (xq@W)*gamma^{-n}/sqrt(D);  K'' = (xk@W)*gamma^m/sqrt(rowsum[m]);  V = xv@W
//   s[b,n] = Q'_n . prefix(K'')_n   (f32-exact)
//   V'_m   = V_m / max(|s_m|,1)
//   H_c    = (K''_c^T V'_c)^T  per chunk;  HS = exclusive chunk prefix of H  (= SE^T)
//   out_n  = Q'_n @ SE + tril(Q' K''^T) @ V'
// All MFMA operands stored K-fast (row-major with contraction axis contiguous):
//   wt = W^T bf16; kb/qb row-major bf16; kbT/vbT = chunk-transposed bf16; HS bf16.

constexpr int B = 8, S = 2048, D = 128;
constexpr int C = 64, NC = S / C;      // chunk size / count
constexpr int BS = B * S;
constexpr int NCH = B * NC;            // total chunks = 256
#define GAMMA_F 0.9865f

typedef __attribute__((ext_vector_type(8))) short short8;      // 8 bf16 (4 VGPRs)
typedef __attribute__((ext_vector_type(8))) unsigned short ushort8;
typedef __attribute__((ext_vector_type(4))) float f32x4;

__device__ inline unsigned short f2bf(float f) {
  unsigned u = __builtin_bit_cast(unsigned, f);
  unsigned r = (u + 0x7FFF + ((u >> 16) & 1)) >> 16;   // RNE
  return (unsigned short)r;
}

__device__ inline short8 pack8(const float* v) {
  short8 r;
#pragma unroll
  for (int i = 0; i < 8; i++) r[i] = (short)f2bf(v[i]);
  return r;
}

// ---------------- K0: per-position decay scalars (f64 closed form) ----------------
__global__ void k_scales(float* __restrict__ qs, float* __restrict__ ks) {
  int n = blockIdx.x * 256 + threadIdx.x;
  if (n >= S) return;
  double g = (double)GAMMA_F;
  double lg = log(g);
  double gmn = exp(-lg * (double)n);   // gamma^{-n}
  double gn  = exp(lg * (double)n);    // gamma^{n}
  double ginv = 1.0 / g;
  double rs = (exp(log(ginv) * (double)(n + 1)) - 1.0) / (ginv - 1.0);
  qs[n] = (float)(gmn / sqrt(128.0));
  ks[n] = (float)(gn / sqrt(rs));
}

// ---------------- K0b: wt = W^T in bf16 ----------------
__global__ __launch_bounds__(256) void k_wt(const float* __restrict__ W,
                                            unsigned short* __restrict__ wt) {
  int idx = blockIdx.x * 256 + threadIdx.x;   // 0..16383
  int k = idx & 127, c = idx >> 7;
  wt[c * 128 + k] = f2bf(W[k * 128 + c]);
}

// ---------------- K1: projections via MFMA ----------------
// grid (BS/64, 3), block 256 (4 waves, 16 rows each, full N=128).
__global__ __launch_bounds__(256) void k_proj(
    const float* __restrict__ xq, const float* __restrict__ xk,
    const float* __restrict__ xv, const unsigned short* __restrict__ wt,
    const float* __restrict__ qs, const float* __restrict__ ks,
    float* __restrict__ qp, float* __restrict__ kp, float* __restrict__ vp,
    unsigned short* __restrict__ qb, unsigned short* __restrict__ kb) {
  int mat = blockIdx.y;
  const float* X = (mat == 0) ? xq : ((mat == 1) ? xk : xv);
  float* O = (mat == 0) ? qp : ((mat == 1) ? kp : vp);
  unsigned short* Ob = (mat == 0) ? qb : ((mat == 1) ? kb : (unsigned short*)0);

  int tid = threadIdx.x, w = tid >> 6, lane = tid & 63;
  int r0 = blockIdx.x * 64 + w * 16;
  int arow = r0 + (lane & 15);
  int kg = (lane >> 4) * 8;

  f32x4 acc[8];
#pragma unroll
  for (int j = 0; j < 8; j++) acc[j] = (f32x4){0.f, 0.f, 0.f, 0.f};

#pragma unroll
  for (int t = 0; t < 4; t++) {
    int k0 = t * 32 + kg;
    const float* ap = X + (size_t)arow * 128 + k0;
    float a8[8];
    *(f32x4*)(a8) = *(const f32x4*)ap;
    *(f32x4*)(a8 + 4) = *(const f32x4*)(ap + 4);
    short8 af = pack8(a8);
#pragma unroll
    for (int j = 0; j < 8; j++) {
      short8 bf = *(const short8*)(wt + (size_t)(j * 16 + (lane & 15)) * 128 + k0);
      acc[j] = __builtin_amdgcn_mfma_f32_16x16x32_bf16(af, bf, acc[j], 0, 0, 0);
    }
  }
  int crow = r0 + (lane >> 4) * 4;
#pragma unroll
  for (int rr = 0; rr < 4; rr++) {
    int row = crow + rr;
    int n = row & (S - 1);
    float sc = (mat == 0) ? qs[n] : ((mat == 1) ? ks[n] : 1.0f);
#pragma unroll
    for (int j = 0; j < 8; j++) {
      int col = j * 16 + (lane & 15);
      float v = acc[j][rr] * sc;
      O[(size_t)row * 128 + col] = v;
      if (Ob) Ob[(size_t)row * 128 + col] = f2bf(v);
    }
  }
}

// ---------------- K2: per-chunk column sums of K'' ----------------
__global__ __launch_bounds__(128) void k_chunksum(const float* __restrict__ kp,
                                                  float* __restrict__ cs) {
  int bc = blockIdx.x;
  int d = threadIdx.x;
  const float* p = kp + (size_t)bc * C * D + d;
  float a = 0.f;
  for (int j = 0; j < C; j++) a += p[j * D];
  cs[bc * D + d] = a;
}

// ---------------- K3: exclusive prefix over chunks ----------------
__global__ __launch_bounds__(128) void k_csprefix(float* __restrict__ cs) {
  int b = blockIdx.x, d = threadIdx.x;
  float run = 0.f;
  for (int c = 0; c < NC; c++) {
    int idx = (b * NC + c) * D + d;
    float t = cs[idx];
    cs[idx] = run;
    run += t;
  }
}

// ---------------- K4: s = Q'.prefix(K''); emit kbT, vbT (bf16, chunk-transposed) ----
__global__ __launch_bounds__(128) void k_svs(
    const float* __restrict__ qp, const float* __restrict__ kp,
    const float* __restrict__ vp, const float* __restrict__ cs,
    unsigned short* __restrict__ kbT, unsigned short* __restrict__ vbT) {
  __shared__ float ps[C][D + 1];
  __shared__ float sl[C];
  __shared__ unsigned short raw[C][D];   // 16 KB transpose buffer
  int bc = blockIdx.x;
  int d = threadIdx.x;
  size_t base = (size_t)bc * C * D;
  float run = cs[bc * D + d];
  for (int j = 0; j < C; j++) {
    float v = kp[base + (size_t)j * D + d];
    run += v;
    ps[j][d] = run;
    raw[j][d] = f2bf(v);
  }
  __syncthreads();
  {  // s-dot, f32-exact
    int j = d >> 1, h = d & 1;
    const float* q = qp + base + (size_t)j * D + h * 64;
    float part = 0.f;
#pragma unroll 8
    for (int i = 0; i < 64; i++) part = fmaf(q[i], ps[j][h * 64 + i], part);
    part += __shfl_xor(part, 1);
    if (h == 0) sl[j] = part;
  }
  // kbT[d][m] = bf16(K''[m][d])
  {
    unsigned short* dst = kbT + (size_t)bc * D * C + (size_t)d * C;
#pragma unroll
    for (int mg = 0; mg < 8; mg++) {
      ushort8 pk;
#pragma unroll
      for (int i = 0; i < 8; i++) pk[i] = raw[mg * 8 + i][d];
      *(ushort8*)(dst + mg * 8) = pk;
    }
  }
  __syncthreads();   // sl ready; raw free to overwrite
  for (int j = 0; j < C; j++) {
    float cdiv = fmaxf(fabsf(sl[j]), 1.0f);
    raw[j][d] = f2bf(vp[base + (size_t)j * D + d] / cdiv);
  }
  __syncthreads();
  {
    unsigned short* dst = vbT + (size_t)bc * D * C + (size_t)d * C;
#pragma unroll
    for (int mg = 0; mg < 8; mg++) {
      ushort8 pk;
#pragma unroll
      for (int i = 0; i < 8; i++) pk[i] = raw[mg * 8 + i][d];
      *(ushort8*)(dst + mg * 8) = pk;
    }
  }
}

// ---------------- K5: H_c[d2][d1] = sum_m V'[m][d2] K''[m][d1]  (= G_c^T) --------
// grid NCH, block 256 (4 waves; wave w: d2 in [32w,32w+32)).
__global__ __launch_bounds__(256) void k_gmat(
    const unsigned short* __restrict__ kbT, const unsigned short* __restrict__ vbT,
    float* __restrict__ G) {
  int bc = blockIdx.x, tid = threadIdx.x, w = tid >> 6, lane = tid & 63;
  const unsigned short* kt = kbT + (size_t)bc * D * C;
  const unsigned short* vt = vbT + (size_t)bc * D * C;
  int kg = (lane >> 4) * 8;
  f32x4 acc[2][8];
#pragma unroll
  for (int i = 0; i < 2; i++)
#pragma unroll
    for (int j = 0; j < 8; j++) acc[i][j] = (f32x4){0.f, 0.f, 0.f, 0.f};
#pragma unroll
  for (int t = 0; t < 2; t++) {
    int k0 = t * 32 + kg;
    short8 a[2];
#pragma unroll
    for (int i = 0; i < 2; i++)
      a[i] = *(const short8*)(vt + (size_t)(w * 32 + i * 16 + (lane & 15)) * C + k0);
#pragma unroll
    for (int j = 0; j < 8; j++) {
      short8 bf = *(const short8*)(kt + (size_t)(j * 16 + (lane & 15)) * C + k0);
#pragma unroll
      for (int i = 0; i < 2; i++)
        acc[i][j] = __builtin_amdgcn_mfma_f32_16x16x32_bf16(a[i], bf, acc[i][j], 0, 0, 0);
    }
  }
  float* g = G + (size_t)bc * D * D;
#pragma unroll
  for (int i = 0; i < 2; i++)
#pragma unroll
    for (int j = 0; j < 8; j++)
#pragma unroll
      for (int rr = 0; rr < 4; rr++)
        g[(size_t)(w * 32 + i * 16 + (lane >> 4) * 4 + rr) * D + j * 16 + (lane & 15)] =
            acc[i][j][rr];
}

// ---------------- K6: HS = exclusive chunk prefix of H, bf16 ----------------
__global__ __launch_bounds__(128) void k_gscan(const float* __restrict__ G,
                                               unsigned short* __restrict__ Hb) {
  int b = blockIdx.x, d2 = blockIdx.y, d1 = threadIdx.x;
  float run = 0.f;
  for (int c = 0; c < NC; c++) {
    size_t idx = (((size_t)(b * NC + c) * D) + d2) * D + d1;
    Hb[idx] = f2bf(run);
    run += G[idx];
  }
}

// ---------------- K7: out = Q'@SE + tril(Q'K''^T)@V' ----------------
// grid NCH, block 256 (4 waves; wave w: rows [16w,16w+16)).
__global__ __launch_bounds__(256) void k_out(
    const unsigned short* __restrict__ qb, const unsigned short* __restrict__ kb,
    const unsigned short* __restrict__ vbT, const unsigned short* __restrict__ Hb,
    float* __restrict__ out) {
  __shared__ unsigned short al[64][72];   // 9 KB masked-score tile, bf16
  int bc = blockIdx.x, tid = threadIdx.x, w = tid >> 6, lane = tid & 63;
  size_t base = (size_t)bc * C * D;
  int kg = (lane >> 4) * 8;
  int arow = w * 16 + (lane & 15);
  int crow = w * 16 + (lane >> 4) * 4;

  // phase 1: A = tril(Q'c @ K''c^T), 64x64
  f32x4 a1[4];
#pragma unroll
  for (int m = 0; m < 4; m++) a1[m] = (f32x4){0.f, 0.f, 0.f, 0.f};
#pragma unroll
  for (int t = 0; t < 4; t++) {
    int k0 = t * 32 + kg;
    short8 af = *(const short8*)(qb + base + (size_t)arow * D + k0);
#pragma unroll
    for (int mt = 0; mt < 4; mt++) {
      short8 bf = *(const short8*)(kb + base + (size_t)(mt * 16 + (lane & 15)) * D + k0);
      a1[mt] = __builtin_amdgcn_mfma_f32_16x16x32_bf16(af, bf, a1[mt], 0, 0, 0);
    }
  }
#pragma unroll
  for (int mt = 0; mt < 4; mt++)
#pragma unroll
    for (int rr = 0; rr < 4; rr++) {
      int n_l = crow + rr, m_l = mt * 16 + (lane & 15);
      al[n_l][m_l] = (n_l >= m_l) ? f2bf(a1[mt][rr]) : (unsigned short)0;
    }
  __syncthreads();

  // phase 2: inter (Q'@SE via HS) + intra (A@V' via vbT)
  f32x4 acc[8];
#pragma unroll
  for (int j = 0; j < 8; j++) acc[j] = (f32x4){0.f, 0.f, 0.f, 0.f};
  const unsigned short* hrow = Hb + (size_t)bc * D * D;
#pragma unroll
  for (int t = 0; t < 4; t++) {
    int k0 = t * 32 + kg;
    short8 af = *(const short8*)(qb + base + (size_t)arow * D + k0);
#pragma unroll
    for (int j = 0; j < 8; j++) {
      short8 bf = *(const short8*)(hrow + (size_t)(j * 16 + (lane & 15)) * D + k0);
      acc[j] = __builtin_amdgcn_mfma_f32_16x16x32_bf16(af, bf, acc[j], 0, 0, 0);
    }
  }
  const unsigned short* vt = vbT + (size_t)bc * D * C;
#pragma unroll
  for (int t = 0; t < 2; t++) {
    int k0 = t * 32 + kg;
    short8 af = *(const short8*)(&al[arow][k0]);
#pragma unroll
    for (int j = 0; j < 8; j++) {
      short8 bf = *(const short8*)(vt + (size_t)(j * 16 + (lane & 15)) * C + k0);
      acc[j] = __builtin_amdgcn_mfma_f32_16x16x32_bf16(af, bf, acc[j], 0, 0, 0);
    }
  }
#pragma unroll
  for (int j = 0; j < 8; j++)
#pragma unroll
    for (int rr = 0; rr < 4; rr++)
      out[base + (size_t)(crow + rr) * D + j * 16 + (lane & 15)] = acc[j][rr];
}

extern "C" void kernel_launch(void* const* d_in, const int* in_sizes, int n_in,
                              void* d_out, int out_size, void* d_ws, size_t ws_size,
                              hipStream_t stream) {
  const float* xq = (const float*)d_in[0];
  const float* xk = (const float*)d_in[1];
  const float* xv = (const float*)d_in[2];
  const float* W  = (const float*)d_in[3];
  float* out = (float*)d_out;

  char* p = (char*)d_ws;
  float* qp = (float*)p;                 p += (size_t)BS * D * 4;
  float* kp = (float*)p;                 p += (size_t)BS * D * 4;
  float* vp = (float*)p;                 p += (size_t)BS * D * 4;
  float* G  = (float*)p;                 p += (size_t)NCH * D * D * 4;
  float* cs = (float*)p;                 p += (size_t)NCH * D * 4;
  float* qs = (float*)p;                 p += (size_t)S * 4;
  float* ks = (float*)p;                 p += (size_t)S * 4;
  unsigned short* qb  = (unsigned short*)p;  p += (size_t)BS * D * 2;
  unsigned short* kb  = (unsigned short*)p;  p += (size_t)BS * D * 2;
  unsigned short* kbT = (unsigned short*)p;  p += (size_t)NCH * D * C * 2;
  unsigned short* vbT = (unsigned short*)p;  p += (size_t)NCH * D * C * 2;
  unsigned short* Hb  = (unsigned short*)p;  p += (size_t)NCH * D * D * 2;
  unsigned short* wt  = (unsigned short*)p;  p += (size_t)D * D * 2;

  hipLaunchKernelGGL(k_scales, dim3(S / 256), dim3(256), 0, stream, qs, ks);
  hipLaunchKernelGGL(k_wt, dim3(D * D / 256), dim3(256), 0, stream, W, wt);
  hipLaunchKernelGGL(k_proj, dim3(BS / 64, 3), dim3(256), 0, stream,
                     xq, xk, xv, wt, qs, ks, qp, kp, vp, qb, kb);
  hipLaunchKernelGGL(k_chunksum, dim3(NCH), dim3(128), 0, stream, kp, cs);
  hipLaunchKernelGGL(k_csprefix, dim3(B), dim3(128), 0, stream, cs);
  hipLaunchKernelGGL(k_svs, dim3(NCH), dim3(128), 0, stream, qp, kp, vp, cs, kbT, vbT);
  hipLaunchKernelGGL(k_gmat, dim3(NCH), dim3(256), 0, stream, kbT, vbT, G);
  hipLaunchKernelGGL(k_gscan, dim3(B, D), dim3(128), 0, stream, G, Hb);
  hipLaunchKernelGGL(k_out, dim3(NCH), dim3(256), 0, stream, qb, kb, vbT, Hb, out);
}

// Round 4
// 60.483 us; speedup vs baseline: 1.9385x; 1.2575x over previous
//
#include <hip/hip_runtime.h>
#include <math.h>

// Retention via chunked linear attention, all-bf16-intermediate edition.
//   Q' = (xq@W)*gamma^{-n}/sqrt(D);  K'' = (xk@W)*gamma^m/sqrt(rowsum[m]);  V = xv@W
//   s[b,n] = Q'_n . prefix(K'')_n   (f32 accumulation over bf16 operands)
//   V'_m   = V_m / max(|s_m|,1)
//   H_c    = (K''_c^T V'_c)^T  per chunk (bf16);  HS = exclusive chunk prefix (bf16)
//   out_n  = Q'_n @ SE + tril(Q' K''^T) @ V'
// All MFMA operands K-fast. Chunk size C=64 == k_proj row-block => chunk sums fused.

constexpr int B = 8, S = 2048, D = 128;
constexpr int C = 64, NC = S / C;      // 32 chunks/batch
constexpr int BS = B * S;
constexpr int NCH = B * NC;            // 256 chunks total
#define GAMMA_F 0.9865f

typedef __attribute__((ext_vector_type(8))) short short8;      // 8 bf16
typedef __attribute__((ext_vector_type(8))) unsigned short ushort8;
typedef __attribute__((ext_vector_type(4))) float f32x4;

__device__ inline unsigned short f2bf(float f) {
  unsigned u = __builtin_bit_cast(unsigned, f);
  return (unsigned short)((u + 0x7FFF + ((u >> 16) & 1)) >> 16);   // RNE
}
__device__ inline float bf2f(unsigned short h) {
  return __builtin_bit_cast(float, (unsigned)h << 16);
}

// ---------------- K0: wt = W^T bf16 (blocks 0..63) + decay scalars (64..71) ------
__global__ void k_init(const float* __restrict__ W, unsigned short* __restrict__ wt,
                       float* __restrict__ qs, float* __restrict__ ks) {
  int bid = blockIdx.x, tid = threadIdx.x;
  if (bid < 64) {
    int idx = bid * 256 + tid;
    int k = idx & 127, c = idx >> 7;
    wt[c * 128 + k] = f2bf(W[k * 128 + c]);
  } else {
    int n = (bid - 64) * 256 + tid;
    if (n < S) {
      double g = (double)GAMMA_F;
      double lg = log(g);
      double gmn = exp(-lg * (double)n);
      double gn  = exp(lg * (double)n);
      double ginv = 1.0 / g;
      double rs = (exp(log(ginv) * (double)(n + 1)) - 1.0) / (ginv - 1.0);
      qs[n] = (float)(gmn / sqrt(128.0));
      ks[n] = (float)(gn / sqrt(rs));
    }
  }
}

// ---------------- K1: projections via MFMA, bf16 out; fused chunk col-sums -------
// grid (NCH, 3), block 256 (4 waves x 16 rows). One block == one chunk.
__global__ __launch_bounds__(256) void k_proj(
    const float* __restrict__ xq, const float* __restrict__ xk,
    const float* __restrict__ xv, const unsigned short* __restrict__ wt,
    const float* __restrict__ qs, const float* __restrict__ ks,
    unsigned short* __restrict__ qb, unsigned short* __restrict__ kb,
    unsigned short* __restrict__ vb, float* __restrict__ cs) {
  __shared__ float css[4][128];
  int mat = blockIdx.y;
  const float* X = (mat == 0) ? xq : ((mat == 1) ? xk : xv);
  unsigned short* Ob = (mat == 0) ? qb : ((mat == 1) ? kb : vb);

  int tid = threadIdx.x, w = tid >> 6, lane = tid & 63;
  int bc = blockIdx.x;
  int r0 = bc * 64 + w * 16;
  int arow = r0 + (lane & 15);
  int kg = (lane >> 4) * 8;

  f32x4 acc[8];
#pragma unroll
  for (int j = 0; j < 8; j++) acc[j] = (f32x4){0.f, 0.f, 0.f, 0.f};

#pragma unroll
  for (int t = 0; t < 4; t++) {
    int k0 = t * 32 + kg;
    const float* ap = X + (size_t)arow * 128 + k0;
    float a8[8];
    *(f32x4*)(a8) = *(const f32x4*)ap;
    *(f32x4*)(a8 + 4) = *(const f32x4*)(ap + 4);
    short8 af;
#pragma unroll
    for (int i = 0; i < 8; i++) af[i] = (short)f2bf(a8[i]);
#pragma unroll
    for (int j = 0; j < 8; j++) {
      short8 bf = *(const short8*)(wt + (size_t)(j * 16 + (lane & 15)) * 128 + k0);
      acc[j] = __builtin_amdgcn_mfma_f32_16x16x32_bf16(af, bf, acc[j], 0, 0, 0);
    }
  }
  int crow = r0 + (lane >> 4) * 4;
  float csp[8];
#pragma unroll
  for (int j = 0; j < 8; j++) csp[j] = 0.f;
#pragma unroll
  for (int rr = 0; rr < 4; rr++) {
    int row = crow + rr;
    int n = row & (S - 1);
    float sc = (mat == 0) ? qs[n] : ((mat == 1) ? ks[n] : 1.0f);
#pragma unroll
    for (int j = 0; j < 8; j++) {
      float v = acc[j][rr] * sc;
      Ob[(size_t)row * 128 + j * 16 + (lane & 15)] = f2bf(v);
      csp[j] += v;
    }
  }
  if (mat == 1) {
#pragma unroll
    for (int j = 0; j < 8; j++) {
      csp[j] += __shfl_xor(csp[j], 16);
      csp[j] += __shfl_xor(csp[j], 32);
    }
    if ((lane >> 4) == 0)
#pragma unroll
      for (int j = 0; j < 8; j++) css[w][j * 16 + lane] = csp[j];
  }
  __syncthreads();
  if (mat == 1 && tid < 128)
    cs[bc * 128 + tid] = css[0][tid] + css[1][tid] + css[2][tid] + css[3][tid];
}

// ---------------- K2: exclusive prefix of chunk sums (register-staged) ----------
__global__ __launch_bounds__(128) void k_csprefix(float* __restrict__ cs) {
  int b = blockIdx.x, d = threadIdx.x;
  float v[NC];
#pragma unroll
  for (int c = 0; c < NC; c++) v[c] = cs[(b * NC + c) * D + d];
  float run = 0.f;
#pragma unroll
  for (int c = 0; c < NC; c++) {
    cs[(b * NC + c) * D + d] = run;
    run += v[c];
  }
}

// ---------------- K3: s = Q'.prefix(K''); V'= V/cdiv; emit kbT, vbT -------------
// grid NCH, block 128.
__global__ __launch_bounds__(128) void k_svs(
    const unsigned short* __restrict__ qb, const unsigned short* __restrict__ kb,
    const unsigned short* __restrict__ vb, const float* __restrict__ cs,
    unsigned short* __restrict__ kbT, unsigned short* __restrict__ vbT) {
  __shared__ unsigned short kraw[64][136];   // padded: transpose-gather spreads banks
  __shared__ float ps[64][129];
  __shared__ float sl[64];
  int bc = blockIdx.x, tid = threadIdx.x;
  size_t base = (size_t)bc * C * D;
  // A: load K'' chunk (bf16)
#pragma unroll
  for (int i = 0; i < 8; i++) {
    int e = (i * 128 + tid) * 8;
    *(ushort8*)&kraw[e >> 7][e & 127] = *(const ushort8*)(kb + base + e);
  }
  __syncthreads();
  // B: inclusive prefix per column d (f32 accum, chunk offset from cs)
  {
    float run = cs[bc * 128 + tid];
#pragma unroll
    for (int j = 0; j < 64; j++) {
      run += bf2f(kraw[j][tid]);
      ps[j][tid] = run;
    }
  }
  __syncthreads();
  // C: s-dot (2 threads per row)
  {
    int j = tid >> 1, h = tid & 1;
    const unsigned short* q = qb + base + (size_t)j * 128 + h * 64;
    float dot = 0.f;
#pragma unroll
    for (int i0 = 0; i0 < 8; i0++) {
      ushort8 q8 = *(const ushort8*)(q + i0 * 8);
#pragma unroll
      for (int ii = 0; ii < 8; ii++)
        dot = fmaf(bf2f(q8[ii]), ps[j][h * 64 + i0 * 8 + ii], dot);
    }
    dot += __shfl_xor(dot, 1);
    if (h == 0) sl[j] = dot;
  }
  // D: kbT[d][m] transpose write (kraw stable)
  {
    unsigned short* dst = kbT + (size_t)bc * D * C + (size_t)tid * C;
#pragma unroll
    for (int mg = 0; mg < 8; mg++) {
      ushort8 pk;
#pragma unroll
      for (int i = 0; i < 8; i++) pk[i] = kraw[mg * 8 + i][tid];
      *(ushort8*)(dst + mg * 8) = pk;
    }
  }
  __syncthreads();
  // E: load V, scale by 1/max(|s|,1), stage into kraw
#pragma unroll
  for (int i = 0; i < 8; i++) {
    int e = (i * 128 + tid) * 8;
    int row = e >> 7, col = e & 127;
    ushort8 v8 = *(const ushort8*)(vb + base + e);
    float inv = 1.0f / fmaxf(fabsf(sl[row]), 1.0f);
    ushort8 o;
#pragma unroll
    for (int ii = 0; ii < 8; ii++) o[ii] = f2bf(bf2f(v8[ii]) * inv);
    *(ushort8*)&kraw[row][col] = o;
  }
  __syncthreads();
  // F: vbT transpose write
  {
    unsigned short* dst = vbT + (size_t)bc * D * C + (size_t)tid * C;
#pragma unroll
    for (int mg = 0; mg < 8; mg++) {
      ushort8 pk;
#pragma unroll
      for (int i = 0; i < 8; i++) pk[i] = kraw[mg * 8 + i][tid];
      *(ushort8*)(dst + mg * 8) = pk;
    }
  }
}

// ---------------- K4: Hc[d2][d1] = sum_m V'[m][d2] K''[m][d1]  (bf16 out) -------
// grid NCH, block 256 (4 waves; wave w: d2 in [32w,32w+32)).
__global__ __launch_bounds__(256) void k_gmat(
    const unsigned short* __restrict__ kbT, const unsigned short* __restrict__ vbT,
    unsigned short* __restrict__ Hc) {
  int bc = blockIdx.x, tid = threadIdx.x, w = tid >> 6, lane = tid & 63;
  const unsigned short* kt = kbT + (size_t)bc * D * C;
  const unsigned short* vt = vbT + (size_t)bc * D * C;
  int kg = (lane >> 4) * 8;
  f32x4 acc[2][8];
#pragma unroll
  for (int i = 0; i < 2; i++)
#pragma unroll
    for (int j = 0; j < 8; j++) acc[i][j] = (f32x4){0.f, 0.f, 0.f, 0.f};
#pragma unroll
  for (int t = 0; t < 2; t++) {
    int k0 = t * 32 + kg;
    short8 a[2];
#pragma unroll
    for (int i = 0; i < 2; i++)
      a[i] = *(const short8*)(vt + (size_t)(w * 32 + i * 16 + (lane & 15)) * C + k0);
#pragma unroll
    for (int j = 0; j < 8; j++) {
      short8 bf = *(const short8*)(kt + (size_t)(j * 16 + (lane & 15)) * C + k0);
#pragma unroll
      for (int i = 0; i < 2; i++)
        acc[i][j] = __builtin_amdgcn_mfma_f32_16x16x32_bf16(a[i], bf, acc[i][j], 0, 0, 0);
    }
  }
  unsigned short* g = Hc + (size_t)bc * D * D;
#pragma unroll
  for (int i = 0; i < 2; i++)
#pragma unroll
    for (int j = 0; j < 8; j++)
#pragma unroll
      for (int rr = 0; rr < 4; rr++)
        g[(size_t)(w * 32 + i * 16 + (lane >> 4) * 4 + rr) * D + j * 16 + (lane & 15)] =
            f2bf(acc[i][j][rr]);
}

// ---------------- K5: HS = exclusive chunk prefix of Hc (f32 accum, bf16 out) ----
__global__ __launch_bounds__(128) void k_gscan(const unsigned short* __restrict__ Hc,
                                               unsigned short* __restrict__ HS) {
  int b = blockIdx.x, d2 = blockIdx.y, d1 = threadIdx.x;
  float v[NC];
#pragma unroll
  for (int c = 0; c < NC; c++)
    v[c] = bf2f(Hc[(((size_t)(b * NC + c) * D) + d2) * D + d1]);
  float run = 0.f;
#pragma unroll
  for (int c = 0; c < NC; c++) {
    HS[(((size_t)(b * NC + c) * D) + d2) * D + d1] = f2bf(run);
    run += v[c];
  }
}

// ---------------- K6: out = Q'@SE + tril(Q'K''^T)@V' ----------------
// grid NCH, block 256 (4 waves; wave w: rows [16w,16w+16)).
__global__ __launch_bounds__(256) void k_out(
    const unsigned short* __restrict__ qb, const unsigned short* __restrict__ kb,
    const unsigned short* __restrict__ vbT, const unsigned short* __restrict__ HS,
    float* __restrict__ out) {
  __shared__ unsigned short al[64][72];
  int bc = blockIdx.x, tid = threadIdx.x, w = tid >> 6, lane = tid & 63;
  size_t base = (size_t)bc * C * D;
  int kg = (lane >> 4) * 8;
  int arow = w * 16 + (lane & 15);
  int crow = w * 16 + (lane >> 4) * 4;

  // phase 1: A = tril(Q'c @ K''c^T)
  f32x4 a1[4];
#pragma unroll
  for (int m = 0; m < 4; m++) a1[m] = (f32x4){0.f, 0.f, 0.f, 0.f};
#pragma unroll
  for (int t = 0; t < 4; t++) {
    int k0 = t * 32 + kg;
    short8 af = *(const short8*)(qb + base + (size_t)arow * D + k0);
#pragma unroll
    for (int mt = 0; mt < 4; mt++) {
      short8 bf = *(const short8*)(kb + base + (size_t)(mt * 16 + (lane & 15)) * D + k0);
      a1[mt] = __builtin_amdgcn_mfma_f32_16x16x32_bf16(af, bf, a1[mt], 0, 0, 0);
    }
  }
#pragma unroll
  for (int mt = 0; mt < 4; mt++)
#pragma unroll
    for (int rr = 0; rr < 4; rr++) {
      int n_l = crow + rr, m_l = mt * 16 + (lane & 15);
      al[n_l][m_l] = (n_l >= m_l) ? f2bf(a1[mt][rr]) : (unsigned short)0;
    }
  __syncthreads();

  // phase 2: inter (Q'@SE via HS) + intra (A@V' via vbT)
  f32x4 acc[8];
#pragma unroll
  for (int j = 0; j < 8; j++) acc[j] = (f32x4){0.f, 0.f, 0.f, 0.f};
  const unsigned short* hrow = HS + (size_t)bc * D * D;
#pragma unroll
  for (int t = 0; t < 4; t++) {
    int k0 = t * 32 + kg;
    short8 af = *(const short8*)(qb + base + (size_t)arow * D + k0);
#pragma unroll
    for (int j = 0; j < 8; j++) {
      short8 bf = *(const short8*)(hrow + (size_t)(j * 16 + (lane & 15)) * D + k0);
      acc[j] = __builtin_amdgcn_mfma_f32_16x16x32_bf16(af, bf, acc[j], 0, 0, 0);
    }
  }
  const unsigned short* vt = vbT + (size_t)bc * D * C;
#pragma unroll
  for (int t = 0; t < 2; t++) {
    int k0 = t * 32 + kg;
    short8 af = *(const short8*)(&al[arow][k0]);
#pragma unroll
    for (int j = 0; j < 8; j++) {
      short8 bf = *(const short8*)(vt + (size_t)(j * 16 + (lane & 15)) * C + k0);
      acc[j] = __builtin_amdgcn_mfma_f32_16x16x32_bf16(af, bf, acc[j], 0, 0, 0);
    }
  }
#pragma unroll
  for (int j = 0; j < 8; j++)
#pragma unroll
    for (int rr = 0; rr < 4; rr++)
      out[base + (size_t)(crow + rr) * D + j * 16 + (lane & 15)] = acc[j][rr];
}

extern "C" void kernel_launch(void* const* d_in, const int* in_sizes, int n_in,
                              void* d_out, int out_size, void* d_ws, size_t ws_size,
                              hipStream_t stream) {
  const float* xq = (const float*)d_in[0];
  const float* xk = (const float*)d_in[1];
  const float* xv = (const float*)d_in[2];
  const float* W  = (const float*)d_in[3];
  float* out = (float*)d_out;

  char* p = (char*)d_ws;
  unsigned short* qb  = (unsigned short*)p;  p += (size_t)BS * D * 2;
  unsigned short* kb  = (unsigned short*)p;  p += (size_t)BS * D * 2;
  unsigned short* vb  = (unsigned short*)p;  p += (size_t)BS * D * 2;
  unsigned short* kbT = (unsigned short*)p;  p += (size_t)NCH * D * C * 2;
  unsigned short* vbT = (unsigned short*)p;  p += (size_t)NCH * D * C * 2;
  unsigned short* Hc  = (unsigned short*)p;  p += (size_t)NCH * D * D * 2;
  unsigned short* HS  = (unsigned short*)p;  p += (size_t)NCH * D * D * 2;
  unsigned short* wt  = (unsigned short*)p;  p += (size_t)D * D * 2;
  float* cs = (float*)p;                     p += (size_t)NCH * D * 4;
  float* qs = (float*)p;                     p += (size_t)S * 4;
  float* ks = (float*)p;                     p += (size_t)S * 4;

  hipLaunchKernelGGL(k_init, dim3(72), dim3(256), 0, stream, W, wt, qs, ks);
  hipLaunchKernelGGL(k_proj, dim3(NCH, 3), dim3(256), 0, stream,
                     xq, xk, xv, wt, qs, ks, qb, kb, vb, cs);
  hipLaunchKernelGGL(k_csprefix, dim3(B), dim3(128), 0, stream, cs);
  hipLaunchKernelGGL(k_svs, dim3(NCH), dim3(128), 0, stream, qb, kb, vb, cs, kbT, vbT);
  hipLaunchKernelGGL(k_gmat, dim3(NCH), dim3(256), 0, stream, kbT, vbT, Hc);
  hipLaunchKernelGGL(k_gscan, dim3(B, D), dim3(128), 0, stream, Hc, HS);
  hipLaunchKernelGGL(k_out, dim3(NCH), dim3(256), 0, stream, qb, kb, vbT, HS, out);
}

// Round 5
// 59.706 us; speedup vs baseline: 1.9637x; 1.0130x over previous
//
#include <hip/hip_runtime.h>
#include <math.h>

// Retention via chunked linear attention, 5-launch edition.
//   Q' = (xq@W)*gamma^{-n}/sqrt(D);  K'' = (xk@W)*gamma^m/sqrt(rowsum[m]);  V = xv@W
//   A_c = tril(Q'_c K''_c^T)  (bf16, stored)        [intra-chunk scores]
//   s[n] = rowsum(A_c)[n] + Q'_n . csp_c            (csp = f32 prefix of chunk col-sums)
//   V'_m = V_m / max(|s_m|,1)
//   Hc   = per-chunk (K''^T V')^T;  HS = exclusive chunk prefix (f32 accum, bf16 out)
//   out_n = Q'_n @ SE + A_c @ V'
// All MFMA operands K-fast.

constexpr int B = 8, S = 2048, D = 128;
constexpr int C = 64, NC = S / C;      // 32 chunks/batch
constexpr int BS = B * S;
constexpr int NCH = B * NC;            // 256 chunks
#define GAMMA_F 0.9865f

typedef __attribute__((ext_vector_type(8))) short short8;
typedef __attribute__((ext_vector_type(8))) unsigned short ushort8;
typedef __attribute__((ext_vector_type(4))) float f32x4;

__device__ inline unsigned short f2bf(float f) {
  unsigned u = __builtin_bit_cast(unsigned, f);
  return (unsigned short)((u + 0x7FFF + ((u >> 16) & 1)) >> 16);   // RNE
}
__device__ inline float bf2f(unsigned short h) {
  return __builtin_bit_cast(float, (unsigned)h << 16);
}

// ---------------- K0: wt = W^T bf16 (blocks 0..63) + decay scalars (64..71) ------
__global__ void k_init(const float* __restrict__ W, unsigned short* __restrict__ wt,
                       float* __restrict__ qs, float* __restrict__ ks) {
  int bid = blockIdx.x, tid = threadIdx.x;
  if (bid < 64) {
    int idx = bid * 256 + tid;
    int k = idx & 127, c = idx >> 7;
    wt[c * 128 + k] = f2bf(W[k * 128 + c]);
  } else {
    int n = (bid - 64) * 256 + tid;
    if (n < S) {
      double g = (double)GAMMA_F;
      double lg = log(g);
      double gmn = exp(-lg * (double)n);
      double gn  = exp(lg * (double)n);
      double ginv = 1.0 / g;
      double rs = (exp(log(ginv) * (double)(n + 1)) - 1.0) / (ginv - 1.0);
      qs[n] = (float)(gmn / sqrt(128.0));
      ks[n] = (float)(gn / sqrt(rs));
    }
  }
}

// ---------------- K1: projections via MFMA, bf16 out; fused chunk col-sums -------
__global__ __launch_bounds__(256) void k_proj(
    const float* __restrict__ xq, const float* __restrict__ xk,
    const float* __restrict__ xv, const unsigned short* __restrict__ wt,
    const float* __restrict__ qs, const float* __restrict__ ks,
    unsigned short* __restrict__ qb, unsigned short* __restrict__ kb,
    unsigned short* __restrict__ vb, float* __restrict__ cs) {
  __shared__ float css[4][128];
  int mat = blockIdx.y;
  const float* X = (mat == 0) ? xq : ((mat == 1) ? xk : xv);
  unsigned short* Ob = (mat == 0) ? qb : ((mat == 1) ? kb : vb);

  int tid = threadIdx.x, w = tid >> 6, lane = tid & 63;
  int bc = blockIdx.x;
  int r0 = bc * 64 + w * 16;
  int arow = r0 + (lane & 15);
  int kg = (lane >> 4) * 8;

  f32x4 acc[8];
#pragma unroll
  for (int j = 0; j < 8; j++) acc[j] = (f32x4){0.f, 0.f, 0.f, 0.f};

#pragma unroll
  for (int t = 0; t < 4; t++) {
    int k0 = t * 32 + kg;
    const float* ap = X + (size_t)arow * 128 + k0;
    float a8[8];
    *(f32x4*)(a8) = *(const f32x4*)ap;
    *(f32x4*)(a8 + 4) = *(const f32x4*)(ap + 4);
    short8 af;
#pragma unroll
    for (int i = 0; i < 8; i++) af[i] = (short)f2bf(a8[i]);
#pragma unroll
    for (int j = 0; j < 8; j++) {
      short8 bf = *(const short8*)(wt + (size_t)(j * 16 + (lane & 15)) * 128 + k0);
      acc[j] = __builtin_amdgcn_mfma_f32_16x16x32_bf16(af, bf, acc[j], 0, 0, 0);
    }
  }
  int crow = r0 + (lane >> 4) * 4;
  float csp[8];
#pragma unroll
  for (int j = 0; j < 8; j++) csp[j] = 0.f;
#pragma unroll
  for (int rr = 0; rr < 4; rr++) {
    int row = crow + rr;
    int n = row & (S - 1);
    float sc = (mat == 0) ? qs[n] : ((mat == 1) ? ks[n] : 1.0f);
#pragma unroll
    for (int j = 0; j < 8; j++) {
      float v = acc[j][rr] * sc;
      Ob[(size_t)row * 128 + j * 16 + (lane & 15)] = f2bf(v);
      csp[j] += v;
    }
  }
  if (mat == 1) {
#pragma unroll
    for (int j = 0; j < 8; j++) {
      csp[j] += __shfl_xor(csp[j], 16);
      csp[j] += __shfl_xor(csp[j], 32);
    }
    if ((lane >> 4) == 0)
#pragma unroll
      for (int j = 0; j < 8; j++) css[w][j * 16 + lane] = csp[j];
  }
  __syncthreads();
  if (mat == 1 && tid < 128)
    cs[bc * 128 + tid] = css[0][tid] + css[1][tid] + css[2][tid] + css[3][tid];
}

// ---------------- K2: A-tile + s + V' + transposes + Hc, all fused --------------
// grid NCH, block 256 (4 waves).
__global__ __launch_bounds__(256) void k_mid(
    const unsigned short* __restrict__ qb, const unsigned short* __restrict__ kb,
    const unsigned short* __restrict__ vb, const float* __restrict__ cs,
    unsigned short* __restrict__ al, unsigned short* __restrict__ vbT,
    unsigned short* __restrict__ Hc) {
  __shared__ unsigned short kraw[64][136];  // 17.4 KB staging (row-major chunk)
  __shared__ unsigned short kT[128][72];    // 18.4 KB K''^T (m-fast)
  __shared__ unsigned short vT[128][72];    // 18.4 KB V'^T
  __shared__ float csp[128];
  __shared__ float invl[64];
  int bc = blockIdx.x, b = bc >> 5, c = bc & 31;
  int tid = threadIdx.x, w = tid >> 6, lane = tid & 63;
  size_t base = (size_t)bc * C * D;
  int kg = (lane >> 4) * 8;
  int arow = w * 16 + (lane & 15);
  int crow = w * 16 + (lane >> 4) * 4;

  // csp[d] = sum over prior chunks of K'' column sums (f32)
  if (tid < 128) {
    float a = 0.f;
    for (int cc = 0; cc < c; cc++) a += cs[(size_t)(b * NC + cc) * D + tid];
    csp[tid] = a;
  }

  // A = tril(Q K^T), write bf16 to global; row-sums for s
  f32x4 a1[4];
#pragma unroll
  for (int m = 0; m < 4; m++) a1[m] = (f32x4){0.f, 0.f, 0.f, 0.f};
#pragma unroll
  for (int t = 0; t < 4; t++) {
    int k0 = t * 32 + kg;
    short8 af = *(const short8*)(qb + base + (size_t)arow * D + k0);
#pragma unroll
    for (int mt = 0; mt < 4; mt++) {
      short8 bf = *(const short8*)(kb + base + (size_t)(mt * 16 + (lane & 15)) * D + k0);
      a1[mt] = __builtin_amdgcn_mfma_f32_16x16x32_bf16(af, bf, a1[mt], 0, 0, 0);
    }
  }
  unsigned short* alg = al + (size_t)bc * 64 * 64;
  float rsum[4] = {0.f, 0.f, 0.f, 0.f};
#pragma unroll
  for (int mt = 0; mt < 4; mt++)
#pragma unroll
    for (int rr = 0; rr < 4; rr++) {
      int n_l = crow + rr, m_l = mt * 16 + (lane & 15);
      float mv = (n_l >= m_l) ? a1[mt][rr] : 0.f;
      alg[n_l * 64 + m_l] = f2bf(mv);
      rsum[rr] += mv;
    }
#pragma unroll
  for (int rr = 0; rr < 4; rr++) {
    float r = rsum[rr];
    r += __shfl_xor(r, 1); r += __shfl_xor(r, 2);
    r += __shfl_xor(r, 4); r += __shfl_xor(r, 8);
    rsum[rr] = r;
  }
  __syncthreads();   // csp visible
  // s_inter = Q_row . csp; invl = 1/max(|s|,1)
#pragma unroll
  for (int rr = 0; rr < 4; rr++) {
    int row = crow + rr;
    ushort8 q8 = *(const ushort8*)(qb + base + (size_t)row * D + (lane & 15) * 8);
    float dt = 0.f;
#pragma unroll
    for (int ii = 0; ii < 8; ii++) dt += bf2f(q8[ii]) * csp[(lane & 15) * 8 + ii];
    dt += __shfl_xor(dt, 1); dt += __shfl_xor(dt, 2);
    dt += __shfl_xor(dt, 4); dt += __shfl_xor(dt, 8);
    if ((lane & 15) == 0) invl[row] = 1.f / fmaxf(fabsf(rsum[rr] + dt), 1.f);
  }
  // stage K chunk (row-major)
#pragma unroll
  for (int i = 0; i < 4; i++) {
    int e = (i * 256 + tid) * 8;
    *(ushort8*)&kraw[e >> 7][e & 127] = *(const ushort8*)(kb + base + e);
  }
  __syncthreads();   // kraw + invl visible
  // pack kT (uniform-row column gathers: conflict-free)
  {
    int d = tid & 127, mh = tid >> 7;
#pragma unroll
    for (int mg = 0; mg < 4; mg++) {
      ushort8 pk;
#pragma unroll
      for (int i = 0; i < 8; i++) pk[i] = kraw[mh * 32 + mg * 8 + i][d];
      *(ushort8*)&kT[d][mh * 32 + mg * 8] = pk;
    }
  }
  __syncthreads();   // kT done, kraw free
  // V' = V * invl -> kraw
#pragma unroll
  for (int i = 0; i < 4; i++) {
    int e = (i * 256 + tid) * 8;
    int row = e >> 7, col = e & 127;
    ushort8 v8 = *(const ushort8*)(vb + base + e);
    float inv = invl[row];
    ushort8 o;
#pragma unroll
    for (int ii = 0; ii < 8; ii++) o[ii] = f2bf(bf2f(v8[ii]) * inv);
    *(ushort8*)&kraw[row][col] = o;
  }
  __syncthreads();
  {
    int d = tid & 127, mh = tid >> 7;
#pragma unroll
    for (int mg = 0; mg < 4; mg++) {
      ushort8 pk;
#pragma unroll
      for (int i = 0; i < 8; i++) pk[i] = kraw[mh * 32 + mg * 8 + i][d];
      *(ushort8*)&vT[d][mh * 32 + mg * 8] = pk;
    }
  }
  __syncthreads();
  // gmat: Hc[d2][d1] = sum_m V'[m][d2] K''[m][d1]
  f32x4 acc[2][8];
#pragma unroll
  for (int i = 0; i < 2; i++)
#pragma unroll
    for (int j = 0; j < 8; j++) acc[i][j] = (f32x4){0.f, 0.f, 0.f, 0.f};
#pragma unroll
  for (int t = 0; t < 2; t++) {
    int k0 = t * 32 + kg;
    short8 a2[2];
#pragma unroll
    for (int i = 0; i < 2; i++)
      a2[i] = *(const short8*)&vT[w * 32 + i * 16 + (lane & 15)][k0];
#pragma unroll
    for (int j = 0; j < 8; j++) {
      short8 bf = *(const short8*)&kT[j * 16 + (lane & 15)][k0];
#pragma unroll
      for (int i = 0; i < 2; i++)
        acc[i][j] = __builtin_amdgcn_mfma_f32_16x16x32_bf16(a2[i], bf, acc[i][j], 0, 0, 0);
    }
  }
  unsigned short* g = Hc + (size_t)bc * D * D;
#pragma unroll
  for (int i = 0; i < 2; i++)
#pragma unroll
    for (int j = 0; j < 8; j++)
#pragma unroll
      for (int rr = 0; rr < 4; rr++)
        g[(size_t)(w * 32 + i * 16 + (lane >> 4) * 4 + rr) * D + j * 16 + (lane & 15)] =
            f2bf(acc[i][j][rr]);
  // vbT -> global (for k_out intra B-operand)
  {
    int d = tid >> 1, pp = (tid & 1) * 32;
    unsigned short* dst = vbT + (size_t)bc * D * C + (size_t)d * C + pp;
#pragma unroll
    for (int q8i = 0; q8i < 4; q8i++)
      *(ushort8*)(dst + q8i * 8) = *(ushort8*)&vT[d][pp + q8i * 8];
  }
}

// ---------------- K3: HS = exclusive chunk prefix of Hc (vectorized) ------------
// grid (B, 32), block 64. Thread: d2 = y*4 + (t>>4), d1 = (t&15)*8.
__global__ __launch_bounds__(64) void k_gscan(const unsigned short* __restrict__ Hc,
                                              unsigned short* __restrict__ HS) {
  int b = blockIdx.x, gy = blockIdx.y, t = threadIdx.x;
  int d2 = gy * 4 + (t >> 4), d1 = (t & 15) * 8;
  size_t off = ((size_t)(b * NC) * D + d2) * D + d1;
  ushort8 v[NC];
#pragma unroll
  for (int c = 0; c < NC; c++)
    v[c] = *(const ushort8*)(Hc + off + (size_t)c * D * D);
  float run[8];
#pragma unroll
  for (int j = 0; j < 8; j++) run[j] = 0.f;
#pragma unroll
  for (int c = 0; c < NC; c++) {
    ushort8 o;
#pragma unroll
    for (int j = 0; j < 8; j++) {
      o[j] = f2bf(run[j]);
      run[j] += bf2f(v[c][j]);
    }
    *(ushort8*)(HS + off + (size_t)c * D * D) = o;
  }
}

// ---------------- K4: out = Q'@SE + A@V'  (no LDS) ----------------
__global__ __launch_bounds__(256) void k_out(
    const unsigned short* __restrict__ qb, const unsigned short* __restrict__ al,
    const unsigned short* __restrict__ vbT, const unsigned short* __restrict__ HS,
    float* __restrict__ out) {
  int bc = blockIdx.x, tid = threadIdx.x, w = tid >> 6, lane = tid & 63;
  size_t base = (size_t)bc * C * D;
  int kg = (lane >> 4) * 8;
  int arow = w * 16 + (lane & 15);
  int crow = w * 16 + (lane >> 4) * 4;

  f32x4 acc[8];
#pragma unroll
  for (int j = 0; j < 8; j++) acc[j] = (f32x4){0.f, 0.f, 0.f, 0.f};
  const unsigned short* hrow = HS + (size_t)bc * D * D;
#pragma unroll
  for (int t = 0; t < 4; t++) {
    int k0 = t * 32 + kg;
    short8 af = *(const short8*)(qb + base + (size_t)arow * D + k0);
#pragma unroll
    for (int j = 0; j < 8; j++) {
      short8 bf = *(const short8*)(hrow + (size_t)(j * 16 + (lane & 15)) * D + k0);
      acc[j] = __builtin_amdgcn_mfma_f32_16x16x32_bf16(af, bf, acc[j], 0, 0, 0);
    }
  }
  const unsigned short* alg = al + (size_t)bc * 64 * 64;
  const unsigned short* vt = vbT + (size_t)bc * D * C;
#pragma unroll
  for (int t = 0; t < 2; t++) {
    int k0 = t * 32 + kg;
    short8 af = *(const short8*)(alg + (size_t)arow * 64 + k0);
#pragma unroll
    for (int j = 0; j < 8; j++) {
      short8 bf = *(const short8*)(vt + (size_t)(j * 16 + (lane & 15)) * C + k0);
      acc[j] = __builtin_amdgcn_mfma_f32_16x16x32_bf16(af, bf, acc[j], 0, 0, 0);
    }
  }
#pragma unroll
  for (int j = 0; j < 8; j++)
#pragma unroll
    for (int rr = 0; rr < 4; rr++)
      out[base + (size_t)(crow + rr) * D + j * 16 + (lane & 15)] = acc[j][rr];
}

extern "C" void kernel_launch(void* const* d_in, const int* in_sizes, int n_in,
                              void* d_out, int out_size, void* d_ws, size_t ws_size,
                              hipStream_t stream) {
  const float* xq = (const float*)d_in[0];
  const float* xk = (const float*)d_in[1];
  const float* xv = (const float*)d_in[2];
  const float* W  = (const float*)d_in[3];
  float* out = (float*)d_out;

  char* p = (char*)d_ws;
  unsigned short* qb  = (unsigned short*)p;  p += (size_t)BS * D * 2;
  unsigned short* kb  = (unsigned short*)p;  p += (size_t)BS * D * 2;
  unsigned short* vb  = (unsigned short*)p;  p += (size_t)BS * D * 2;
  unsigned short* vbT = (unsigned short*)p;  p += (size_t)NCH * D * C * 2;
  unsigned short* al  = (unsigned short*)p;  p += (size_t)NCH * C * C * 2;
  unsigned short* Hc  = (unsigned short*)p;  p += (size_t)NCH * D * D * 2;
  unsigned short* HS  = (unsigned short*)p;  p += (size_t)NCH * D * D * 2;
  unsigned short* wt  = (unsigned short*)p;  p += (size_t)D * D * 2;
  float* cs = (float*)p;                     p += (size_t)NCH * D * 4;
  float* qs = (float*)p;                     p += (size_t)S * 4;
  float* ks = (float*)p;                     p += (size_t)S * 4;

  hipLaunchKernelGGL(k_init, dim3(72), dim3(256), 0, stream, W, wt, qs, ks);
  hipLaunchKernelGGL(k_proj, dim3(NCH, 3), dim3(256), 0, stream,
                     xq, xk, xv, wt, qs, ks, qb, kb, vb, cs);
  hipLaunchKernelGGL(k_mid, dim3(NCH), dim3(256), 0, stream, qb, kb, vb, cs, al, vbT, Hc);
  hipLaunchKernelGGL(k_gscan, dim3(B, 32), dim3(64), 0, stream, Hc, HS);
  hipLaunchKernelGGL(k_out, dim3(NCH), dim3(256), 0, stream, qb, al, vbT, HS, out);
}